// Round 4
// baseline (223.868 us; speedup 1.0000x reference)
//
#include <hip/hip_runtime.h>

// x_restored: (8192, 3, 20, 20) f32
// x_distorted: (8192, 5) f32
// w1: (128, 5), w2: (1200, 128), b2: (1200,)
// conv_w: (15, 6, 3, 3), conv_b: (15,)
// out: (8192, 5, 3, 20, 20) f32

#define NB 8192

typedef __attribute__((ext_vector_type(8))) short short8;
typedef __attribute__((ext_vector_type(4))) float floatx4;

__device__ inline unsigned short f2bf(float f) {
    unsigned int u = __float_as_uint(f);
    unsigned int r = (u + 0x7FFFu + ((u >> 16) & 1u)) >> 16;
    return (unsigned short)r;
}

// ---------------- Kernel A: h = relu(x_distorted @ w1.T) -> bf16, (B,128) ----------------
__global__ __launch_bounds__(256) void mlp1_kernel(const float* __restrict__ xdist,
                                                   const float* __restrict__ w1,
                                                   unsigned short* __restrict__ hb) {
    int gid = blockIdx.x * 256 + threadIdx.x;
    int b = gid >> 7, j = gid & 127;
    const float* xr = xdist + b * 5;
    const float* wr = w1 + j * 5;
    float s = xr[0] * wr[0];
    s = fmaf(xr[1], wr[1], s);
    s = fmaf(xr[2], wr[2], s);
    s = fmaf(xr[3], wr[3], s);
    s = fmaf(xr[4], wr[4], s);
    hb[gid] = f2bf(fmaxf(s, 0.0f));
}

// ---------------- cast w2 -> bf16 ----------------
__global__ __launch_bounds__(256) void castw2_kernel(const float* __restrict__ w2,
                                                     unsigned short* __restrict__ w2b) {
    int i = blockIdx.x * 256 + threadIdx.x;   // 1200*128 = 153600 exactly
    w2b[i] = f2bf(w2[i]);
}

// ---------------- Kernel B: xd = h @ w2.T + b2 via bf16 MFMA ----------------
// wave-tile 64(M) x 48(N), K=128 in 4 steps of 16x16x32. N = 25*48 = 1200 exact.
__global__ __launch_bounds__(256) void mlp2_mfma(const unsigned short* __restrict__ hb,
                                                 const unsigned short* __restrict__ w2b,
                                                 const float* __restrict__ b2,
                                                 float* __restrict__ xd) {
    const int tid = threadIdx.x;
    const int lane = tid & 63, wv = tid >> 6;
    const int tile = blockIdx.x * 4 + wv;          // 0..3199
    const int mt = tile / 25, nt = tile - mt * 25; // 128 m-tiles x 25 n-tiles
    const int rsel = lane & 15, kg = lane >> 4;

    short8 a[4][4], bfr[3][4];
    #pragma unroll
    for (int mi = 0; mi < 4; ++mi) {
        const unsigned short* ap = hb + (size_t)(mt * 64 + mi * 16 + rsel) * 128 + kg * 8;
        #pragma unroll
        for (int ks = 0; ks < 4; ++ks) a[mi][ks] = *(const short8*)(ap + ks * 32);
    }
    #pragma unroll
    for (int ni = 0; ni < 3; ++ni) {
        const unsigned short* bp = w2b + (size_t)(nt * 48 + ni * 16 + rsel) * 128 + kg * 8;
        #pragma unroll
        for (int ks = 0; ks < 4; ++ks) bfr[ni][ks] = *(const short8*)(bp + ks * 32);
    }
    floatx4 acc[4][3];
    #pragma unroll
    for (int mi = 0; mi < 4; ++mi)
        #pragma unroll
        for (int ni = 0; ni < 3; ++ni)
            acc[mi][ni] = (floatx4){0.f, 0.f, 0.f, 0.f};

    #pragma unroll
    for (int ks = 0; ks < 4; ++ks)
        #pragma unroll
        for (int mi = 0; mi < 4; ++mi)
            #pragma unroll
            for (int ni = 0; ni < 3; ++ni)
                acc[mi][ni] = __builtin_amdgcn_mfma_f32_16x16x32_bf16(
                    a[mi][ks], bfr[ni][ks], acc[mi][ni], 0, 0, 0);

    #pragma unroll
    for (int ni = 0; ni < 3; ++ni) {
        float bias = b2[nt * 48 + ni * 16 + rsel];
        #pragma unroll
        for (int mi = 0; mi < 4; ++mi) {
            #pragma unroll
            for (int r = 0; r < 4; ++r) {
                int m = mt * 64 + mi * 16 + kg * 4 + r;
                xd[(size_t)m * 1200 + nt * 48 + ni * 16 + rsel] = acc[mi][ni][r] + bias;
            }
        }
    }
}

// ---------------- Kernel C: conv(6->15, 3x3 SAME) + Gram-Schmidt, ONE WAVE per sample ----
// Strip layout: lane l (<60) owns row r = l/3, x-range [x0, x0+6], x0 = (l%3)*7
// (strip widths 7/7/6). launch_bounds(64,1): VGPR budget 512 so the 105 live
// accumulators stay in VGPRs (R3's VGPR=100 < 105 -> scratch spills, +76MB writes).
// Output goes through an LDS transpose bounce (reusing xpad) -> float4 coalesced stores.
__global__ __launch_bounds__(64, 1) void conv_gs_kernel(const float* __restrict__ xd,
                                                        const float* __restrict__ xres,
                                                        const float* __restrict__ cw,
                                                        const float* __restrict__ cb,
                                                        float* __restrict__ out) {
    const int b = blockIdx.x;
    const int tid = threadIdx.x;  // 0..63
    __shared__ __align__(16) float xpad[2908];  // 6*22*22 zero-padded planes (+4 pad)

    // zero whole buffer (727 float4)
    float4* xf4 = (float4*)xpad;
    #pragma unroll
    for (int i = 0; i < 12; ++i) {
        int idx = tid + i * 64;
        if (idx < 727) xf4[idx] = make_float4(0.f, 0.f, 0.f, 0.f);
    }
    __syncthreads();

    // interior fill: 600 float4 (channels 0-2 = xd, 3-5 = xres)
    const float* src0 = xd + (size_t)b * 1200;
    const float* src1 = xres + (size_t)b * 1200;
    #pragma unroll
    for (int i = 0; i < 10; ++i) {
        int j = tid + i * 64;
        if (j < 600) {
            float4 v = (j < 300) ? ((const float4*)src0)[j] : ((const float4*)src1)[j - 300];
            int c = j / 100, rr = (j % 100) * 4, y = rr / 20, x = rr % 20;
            float* dst = xpad + c * 484 + (y + 1) * 22 + (x + 1);
            dst[0] = v.x; dst[1] = v.y; dst[2] = v.z; dst[3] = v.w;
        }
    }
    __syncthreads();

    // strip assignment
    const int ll = (tid < 60) ? tid : 59;
    const int r  = ll / 3;
    const int j3 = ll - r * 3;
    const int x0 = j3 * 7;
    const int wbase = r * 22 + x0;   // padded-plane offset of window col 0, ky row 0

    // conv accumulators
    float acc[7][15];
    #pragma unroll
    for (int o = 0; o < 15; ++o) {
        float bo = cb[o];
        #pragma unroll
        for (int s = 0; s < 7; ++s) acc[s][o] = bo;
    }

    #pragma unroll
    for (int ci = 0; ci < 6; ++ci) {
        #pragma unroll
        for (int ky = 0; ky < 3; ++ky) {
            const float* rp = xpad + ci * 484 + ky * 22 + wbase;
            float win[9];
            #pragma unroll
            for (int t = 0; t < 9; ++t) win[t] = rp[t];
            const float* wb = cw + ci * 9 + ky * 3;  // + o*54, uniform -> s_load
            #pragma unroll
            for (int o = 0; o < 15; ++o) {
                float w0 = wb[o * 54 + 0], w1v = wb[o * 54 + 1], w2v = wb[o * 54 + 2];
                #pragma unroll
                for (int s = 0; s < 7; ++s)
                    acc[s][o] = fmaf(win[s], w0,
                                fmaf(win[s + 1], w1v,
                                fmaf(win[s + 2], w2v, acc[s][o])));
            }
        }
    }

    // mask invalid slots: lanes >= 60 entirely; slot 6 of width-6 strips (j3==2)
    const float mAll = (tid < 60) ? 1.f : 0.f;
    const float m6   = (j3 < 2) ? mAll : 0.f;
    #pragma unroll
    for (int o = 0; o < 15; ++o) {
        #pragma unroll
        for (int s = 0; s < 6; ++s) acc[s][o] *= mAll;
        acc[6][o] *= m6;
    }

    // wave-wide butterfly sum
    auto rsum = [](float v) {
        #pragma unroll
        for (int m = 32; m; m >>= 1) v += __shfl_xor(v, m, 64);
        return v;
    };

    float c;
    #define D3(s, i, j) (acc[s][3*(i)] * acc[s][3*(j)] + \
                         acc[s][3*(i)+1] * acc[s][3*(j)+1] + \
                         acc[s][3*(i)+2] * acc[s][3*(j)+2])
    #define DOTL(i, j) (D3(0,i,j) + D3(1,i,j) + D3(2,i,j) + D3(3,i,j) + \
                        D3(4,i,j) + D3(5,i,j) + D3(6,i,j))
    #define DOT(i, j) rsum(DOTL(i, j))
    #define AXPY(i, j) { _Pragma("unroll") for (int s = 0; s < 7; ++s) { \
        acc[s][3*(i)]   = fmaf(-c, acc[s][3*(j)],   acc[s][3*(i)]);   \
        acc[s][3*(i)+1] = fmaf(-c, acc[s][3*(j)+1], acc[s][3*(i)+1]); \
        acc[s][3*(i)+2] = fmaf(-c, acc[s][3*(j)+2], acc[s][3*(i)+2]); } }

    const float inv0 = 1.0f / DOT(0, 0);
    c = DOT(1, 0) * inv0; AXPY(1, 0);
    const float inv1 = 1.0f / DOT(1, 1);
    c = DOT(2, 0) * inv0; AXPY(2, 0);
    c = DOT(2, 1) * inv1; AXPY(2, 1);
    const float inv2 = 1.0f / DOT(2, 2);
    c = DOT(3, 0) * inv0; AXPY(3, 0);
    c = DOT(3, 1) * inv1; AXPY(3, 1);
    c = DOT(3, 2) * inv2; AXPY(3, 2);
    const float inv3 = 1.0f / DOT(3, 3);
    c = DOT(4, 0) * inv0; AXPY(4, 0);
    c = DOT(4, 1) * inv1; AXPY(4, 1);
    c = DOT(4, 2) * inv2; AXPY(4, 2);
    c = DOT(4, 3) * inv3; AXPY(4, 3);
    #undef D3
    #undef DOTL
    #undef DOT
    #undef AXPY

    // ---- output via LDS transpose bounce (xpad is dead now), coalesced float4 stores ----
    const size_t obase = (size_t)b * 6000;
    const int pb = r * 20 + x0;
    #pragma unroll
    for (int chunk = 0; chunk < 3; ++chunk) {
        const int o0 = chunk * 7;
        const int no = (chunk == 2) ? 1 : 7;     // channels in this chunk
        __syncthreads();                          // xpad reusable / prev reads done
        if (tid < 60) {
            #pragma unroll
            for (int oo = 0; oo < no; ++oo) {
                #pragma unroll
                for (int s = 0; s < 7; ++s) {
                    if (s < 6 || j3 < 2)
                        xpad[oo * 400 + pb + s] = acc[s][o0 + oo];
                }
            }
        }
        __syncthreads();
        const int total4 = no * 100;             // float4 count
        float4* dst4 = (float4*)(out + obase + (size_t)o0 * 400);
        #pragma unroll
        for (int k = 0; k < 11; ++k) {
            int k4 = tid + k * 64;
            if (k4 < total4) dst4[k4] = ((const float4*)xpad)[k4];
        }
    }
}

extern "C" void kernel_launch(void* const* d_in, const int* in_sizes, int n_in,
                              void* d_out, int out_size, void* d_ws, size_t ws_size,
                              hipStream_t stream) {
    const float* x_restored  = (const float*)d_in[0];
    const float* x_distorted = (const float*)d_in[1];
    const float* w1          = (const float*)d_in[2];
    const float* w2          = (const float*)d_in[3];
    const float* b2          = (const float*)d_in[4];
    const float* conv_w      = (const float*)d_in[5];
    const float* conv_b      = (const float*)d_in[6];
    float* out = (float*)d_out;

    float* xd = (float*)d_ws;                                         // 39.3 MB
    unsigned short* hb  = (unsigned short*)(xd + (size_t)NB * 1200);  // 2 MB
    unsigned short* w2b = hb + (size_t)NB * 128;                      // 0.3 MB

    mlp1_kernel<<<(NB * 128) / 256, 256, 0, stream>>>(x_distorted, w1, hb);
    castw2_kernel<<<(1200 * 128) / 256, 256, 0, stream>>>(w2, w2b);
    mlp2_mfma<<<(128 * 25) / 4, 256, 0, stream>>>(hb, w2b, b2, xd);
    conv_gs_kernel<<<NB, 64, 0, stream>>>(xd, x_restored, conv_w, conv_b, out);
}

// Round 5
// 218.226 us; speedup vs baseline: 1.0259x; 1.0259x over previous
//
#include <hip/hip_runtime.h>

// x_restored: (8192, 3, 20, 20) f32
// x_distorted: (8192, 5) f32
// w1: (128, 5), w2: (1200, 128), b2: (1200,)
// conv_w: (15, 6, 3, 3), conv_b: (15,)
// out: (8192, 5, 3, 20, 20) f32

#define NB 8192

typedef __attribute__((ext_vector_type(8))) short short8;
typedef __attribute__((ext_vector_type(4))) float floatx4;

__device__ inline unsigned short f2bf(float f) {
    unsigned int u = __float_as_uint(f);
    unsigned int r = (u + 0x7FFFu + ((u >> 16) & 1u)) >> 16;
    return (unsigned short)r;
}

// ---------------- Kernel A: h = relu(x_distorted @ w1.T) -> bf16, (B,128) ----------------
__global__ __launch_bounds__(256) void mlp1_kernel(const float* __restrict__ xdist,
                                                   const float* __restrict__ w1,
                                                   unsigned short* __restrict__ hb) {
    int gid = blockIdx.x * 256 + threadIdx.x;
    int b = gid >> 7, j = gid & 127;
    const float* xr = xdist + b * 5;
    const float* wr = w1 + j * 5;
    float s = xr[0] * wr[0];
    s = fmaf(xr[1], wr[1], s);
    s = fmaf(xr[2], wr[2], s);
    s = fmaf(xr[3], wr[3], s);
    s = fmaf(xr[4], wr[4], s);
    hb[gid] = f2bf(fmaxf(s, 0.0f));
}

// ---------------- cast w2 -> bf16 ----------------
__global__ __launch_bounds__(256) void castw2_kernel(const float* __restrict__ w2,
                                                     unsigned short* __restrict__ w2b) {
    int i = blockIdx.x * 256 + threadIdx.x;   // 1200*128 = 153600 exactly
    w2b[i] = f2bf(w2[i]);
}

// ---------------- Kernel B: xd = h @ w2.T + b2 via bf16 MFMA ----------------
// wave-tile 64(M) x 48(N), K=128 in 4 steps of 16x16x32. N = 25*48 = 1200 exact.
__global__ __launch_bounds__(256) void mlp2_mfma(const unsigned short* __restrict__ hb,
                                                 const unsigned short* __restrict__ w2b,
                                                 const float* __restrict__ b2,
                                                 float* __restrict__ xd) {
    const int tid = threadIdx.x;
    const int lane = tid & 63, wv = tid >> 6;
    const int tile = blockIdx.x * 4 + wv;          // 0..3199
    const int mt = tile / 25, nt = tile - mt * 25; // 128 m-tiles x 25 n-tiles
    const int rsel = lane & 15, kg = lane >> 4;

    short8 a[4][4], bfr[3][4];
    #pragma unroll
    for (int mi = 0; mi < 4; ++mi) {
        const unsigned short* ap = hb + (size_t)(mt * 64 + mi * 16 + rsel) * 128 + kg * 8;
        #pragma unroll
        for (int ks = 0; ks < 4; ++ks) a[mi][ks] = *(const short8*)(ap + ks * 32);
    }
    #pragma unroll
    for (int ni = 0; ni < 3; ++ni) {
        const unsigned short* bp = w2b + (size_t)(nt * 48 + ni * 16 + rsel) * 128 + kg * 8;
        #pragma unroll
        for (int ks = 0; ks < 4; ++ks) bfr[ni][ks] = *(const short8*)(bp + ks * 32);
    }
    floatx4 acc[4][3];
    #pragma unroll
    for (int mi = 0; mi < 4; ++mi)
        #pragma unroll
        for (int ni = 0; ni < 3; ++ni)
            acc[mi][ni] = (floatx4){0.f, 0.f, 0.f, 0.f};

    #pragma unroll
    for (int ks = 0; ks < 4; ++ks)
        #pragma unroll
        for (int mi = 0; mi < 4; ++mi)
            #pragma unroll
            for (int ni = 0; ni < 3; ++ni)
                acc[mi][ni] = __builtin_amdgcn_mfma_f32_16x16x32_bf16(
                    a[mi][ks], bfr[ni][ks], acc[mi][ni], 0, 0, 0);

    #pragma unroll
    for (int ni = 0; ni < 3; ++ni) {
        float bias = b2[nt * 48 + ni * 16 + rsel];
        #pragma unroll
        for (int mi = 0; mi < 4; ++mi) {
            #pragma unroll
            for (int r = 0; r < 4; ++r) {
                int m = mt * 64 + mi * 16 + kg * 4 + r;
                xd[(size_t)m * 1200 + nt * 48 + ni * 16 + rsel] = acc[mi][ni][r] + bias;
            }
        }
    }
}

// Gram index for (i,j), i<=j, packed upper triangle of 5x5 -> 15
#define GIDX(i, j) ((i) * 5 - (i) * ((i) - 1) / 2 + ((j) - (i)))
#define GF(i, j) Gm[((i) <= (j)) ? GIDX(i, j) : GIDX(j, i)]

// ---------------- Kernel C: conv(6->15) + Gram-space GS. 128 threads / sample. ----------
// Thread t (<100) owns 4 adjacent positions p = 4t..4t+3 (quad => float4 store), all 15
// output channels: acc[4][15] = 60 VGPRs. GS is done in coefficient space: the 5x5 Gram
// matrix G = W W^T is reduced ONCE (15 independent values, batched shuffles), then every
// thread redundantly computes the lower-triangular combination matrix A from G (~250
// flops, no communication), and finally out = A * w entirely in registers.
__global__ __launch_bounds__(128, 4) void conv_gs_kernel(const float* __restrict__ xd,
                                                         const float* __restrict__ xres,
                                                         const float* __restrict__ cw,
                                                         const float* __restrict__ cb,
                                                         float* __restrict__ out) {
    const int b = blockIdx.x;
    const int tid = threadIdx.x;  // 0..127
    const int lane = tid & 63, wv = tid >> 6;
    __shared__ __align__(16) float xpad[2908];  // 6*22*22 zero-padded planes (+4)
    __shared__ float gred[2][16];

    // zero pad buffer (727 float4)
    float4* xf4 = (float4*)xpad;
    #pragma unroll
    for (int i = 0; i < 6; ++i) {
        int idx = tid + i * 128;
        if (idx < 727) xf4[idx] = make_float4(0.f, 0.f, 0.f, 0.f);
    }
    __syncthreads();

    // interior fill: 600 float4 (channels 0-2 = xd, 3-5 = xres)
    const float* src0 = xd + (size_t)b * 1200;
    const float* src1 = xres + (size_t)b * 1200;
    #pragma unroll
    for (int i = 0; i < 5; ++i) {
        int j = tid + i * 128;
        if (j < 600) {
            float4 v = (j < 300) ? ((const float4*)src0)[j] : ((const float4*)src1)[j - 300];
            int c = j / 100, rr = (j % 100) * 4, y = rr / 20, x = rr % 20;
            float* dst = xpad + c * 484 + (y + 1) * 22 + (x + 1);
            dst[0] = v.x; dst[1] = v.y; dst[2] = v.z; dst[3] = v.w;
        }
    }
    __syncthreads();

    // quad assignment: positions 4t..4t+3, row y = t/5, x0 = 4*(t%5); never straddles rows
    const int tt = (tid < 100) ? tid : 99;
    const int y = tt / 5, xq = (tt % 5) * 4;
    const int wbase = y * 22 + xq;

    float acc[4][15];
    #pragma unroll
    for (int o = 0; o < 15; ++o) {
        float bo = cb[o];
        #pragma unroll
        for (int s = 0; s < 4; ++s) acc[s][o] = bo;
    }

    #pragma unroll
    for (int ci = 0; ci < 6; ++ci) {
        #pragma unroll
        for (int ky = 0; ky < 3; ++ky) {
            const float* rp = xpad + ci * 484 + ky * 22 + wbase;
            float r0 = rp[0], r1 = rp[1], r2 = rp[2], r3 = rp[3], r4 = rp[4], r5 = rp[5];
            const float* wb = cw + ci * 9 + ky * 3;  // + o*54, uniform -> s_load
            #pragma unroll
            for (int o = 0; o < 15; ++o) {
                float w0 = wb[o * 54 + 0], w1v = wb[o * 54 + 1], w2v = wb[o * 54 + 2];
                acc[0][o] = fmaf(r0, w0, fmaf(r1, w1v, fmaf(r2, w2v, acc[0][o])));
                acc[1][o] = fmaf(r1, w0, fmaf(r2, w1v, fmaf(r3, w2v, acc[1][o])));
                acc[2][o] = fmaf(r2, w0, fmaf(r3, w1v, fmaf(r4, w2v, acc[2][o])));
                acc[3][o] = fmaf(r3, w0, fmaf(r4, w1v, fmaf(r5, w2v, acc[3][o])));
            }
        }
    }

    // zero inactive threads' contributions
    const float mk = (tid < 100) ? 1.f : 0.f;
    #pragma unroll
    for (int o = 0; o < 15; ++o) {
        #pragma unroll
        for (int s = 0; s < 4; ++s) acc[s][o] *= mk;
    }

    // local Gram partials: 15 (i<=j) pairs, 12 FMA each
    float g[15];
    {
        int p = 0;
        #pragma unroll
        for (int i = 0; i < 5; ++i) {
            #pragma unroll
            for (int j = i; j < 5; ++j, ++p) {
                float s0 = 0.f;
                #pragma unroll
                for (int s = 0; s < 4; ++s) {
                    #pragma unroll
                    for (int cc = 0; cc < 3; ++cc)
                        s0 = fmaf(acc[s][3 * i + cc], acc[s][3 * j + cc], s0);
                }
                g[p] = s0;
            }
        }
    }

    // batched wave reduction: 15 independent butterfly chains (pipelined)
    #pragma unroll
    for (int m = 32; m; m >>= 1) {
        #pragma unroll
        for (int v = 0; v < 15; ++v) g[v] += __shfl_xor(g[v], m, 64);
    }
    if (lane == 0) {
        #pragma unroll
        for (int v = 0; v < 15; ++v) gred[wv][v] = g[v];
    }
    __syncthreads();
    float Gm[15];
    #pragma unroll
    for (int v = 0; v < 15; ++v) Gm[v] = gred[0][v] + gred[1][v];

    // redundant per-thread GS in coefficient space (modified-GS ordering)
    float A[5][5];
    #pragma unroll
    for (int i = 0; i < 5; ++i) {
        #pragma unroll
        for (int j = 0; j < 5; ++j) A[i][j] = (i == j) ? 1.f : 0.f;
    }
    #pragma unroll
    for (int j = 0; j < 4; ++j) {
        float v[5];
        #pragma unroll
        for (int r = 0; r < 5; ++r) {
            float s0 = 0.f;
            #pragma unroll
            for (int k = 0; k < 5; ++k)
                if (k <= j) s0 = fmaf(A[j][k], GF(k, r), s0);
            v[r] = s0;
        }
        float dj = 0.f;
        #pragma unroll
        for (int k = 0; k < 5; ++k)
            if (k <= j) dj = fmaf(A[j][k], v[k], dj);
        float rd = 1.0f / dj;
        #pragma unroll
        for (int i = j + 1; i < 5; ++i) {
            float cij = 0.f;
            #pragma unroll
            for (int k = 0; k < 5; ++k)
                if (k <= i) cij = fmaf(A[i][k], v[k], cij);
            cij *= rd;
            #pragma unroll
            for (int k = 0; k < 5; ++k)
                if (k <= j) A[i][k] = fmaf(-cij, A[j][k], A[i][k]);
        }
    }

    // combine in place, descending d so originals of k<d survive
    #pragma unroll
    for (int dd = 4; dd >= 1; --dd) {
        #pragma unroll
        for (int cc = 0; cc < 3; ++cc) {
            #pragma unroll
            for (int s = 0; s < 4; ++s) {
                float val = acc[s][3 * dd + cc];
                #pragma unroll
                for (int k = 0; k < dd; ++k)
                    val = fmaf(A[dd][k], acc[s][3 * k + cc], val);
                acc[s][3 * dd + cc] = val;
            }
        }
    }

    // float4 stores: quad is 4 adjacent positions, 16B-aligned
    if (tid < 100) {
        float* ob = out + (size_t)b * 6000 + 4 * tid;
        #pragma unroll
        for (int o = 0; o < 15; ++o) {
            float4 vv = make_float4(acc[0][o], acc[1][o], acc[2][o], acc[3][o]);
            *(float4*)(ob + o * 400) = vv;
        }
    }
}

extern "C" void kernel_launch(void* const* d_in, const int* in_sizes, int n_in,
                              void* d_out, int out_size, void* d_ws, size_t ws_size,
                              hipStream_t stream) {
    const float* x_restored  = (const float*)d_in[0];
    const float* x_distorted = (const float*)d_in[1];
    const float* w1          = (const float*)d_in[2];
    const float* w2          = (const float*)d_in[3];
    const float* b2          = (const float*)d_in[4];
    const float* conv_w      = (const float*)d_in[5];
    const float* conv_b      = (const float*)d_in[6];
    float* out = (float*)d_out;

    float* xd = (float*)d_ws;                                         // 39.3 MB
    unsigned short* hb  = (unsigned short*)(xd + (size_t)NB * 1200);  // 2 MB
    unsigned short* w2b = hb + (size_t)NB * 128;                      // 0.3 MB

    mlp1_kernel<<<(NB * 128) / 256, 256, 0, stream>>>(x_distorted, w1, hb);
    castw2_kernel<<<(1200 * 128) / 256, 256, 0, stream>>>(w2, w2b);
    mlp2_mfma<<<(128 * 25) / 4, 256, 0, stream>>>(hb, w2b, b2, xd);
    conv_gs_kernel<<<NB, 128, 0, stream>>>(xd, x_restored, conv_w, conv_b, out);
}

// Round 6
// 161.912 us; speedup vs baseline: 1.3827x; 1.3478x over previous
//
#include <hip/hip_runtime.h>

// x_restored: (8192, 3, 20, 20) f32
// x_distorted: (8192, 5) f32
// w1: (128, 5), w2: (1200, 128), b2: (1200,)
// conv_w: (15, 6, 3, 3), conv_b: (15,)
// out: (8192, 5, 3, 20, 20) f32

#define NB 8192

typedef __attribute__((ext_vector_type(8))) short short8;
typedef __attribute__((ext_vector_type(4))) float floatx4;

__device__ inline unsigned short f2bf(float f) {
    unsigned int u = __float_as_uint(f);
    unsigned int r = (u + 0x7FFFu + ((u >> 16) & 1u)) >> 16;
    return (unsigned short)r;
}

// ---------------- Kernel A: h = relu(x_distorted @ w1.T) -> bf16, (B,128) ----------------
__global__ __launch_bounds__(256) void mlp1_kernel(const float* __restrict__ xdist,
                                                   const float* __restrict__ w1,
                                                   unsigned short* __restrict__ hb) {
    int gid = blockIdx.x * 256 + threadIdx.x;
    int b = gid >> 7, j = gid & 127;
    const float* xr = xdist + b * 5;
    const float* wr = w1 + j * 5;
    float s = xr[0] * wr[0];
    s = fmaf(xr[1], wr[1], s);
    s = fmaf(xr[2], wr[2], s);
    s = fmaf(xr[3], wr[3], s);
    s = fmaf(xr[4], wr[4], s);
    hb[gid] = f2bf(fmaxf(s, 0.0f));
}

// ---------------- cast w2 -> bf16 ----------------
__global__ __launch_bounds__(256) void castw2_kernel(const float* __restrict__ w2,
                                                     unsigned short* __restrict__ w2b) {
    int i = blockIdx.x * 256 + threadIdx.x;   // 1200*128 = 153600 exactly
    w2b[i] = f2bf(w2[i]);
}

// ---------------- Kernel B: xd = h @ w2.T + b2 via bf16 MFMA ----------------
__global__ __launch_bounds__(256) void mlp2_mfma(const unsigned short* __restrict__ hb,
                                                 const unsigned short* __restrict__ w2b,
                                                 const float* __restrict__ b2,
                                                 float* __restrict__ xd) {
    const int tid = threadIdx.x;
    const int lane = tid & 63, wv = tid >> 6;
    const int tile = blockIdx.x * 4 + wv;          // 0..3199
    const int mt = tile / 25, nt = tile - mt * 25;
    const int rsel = lane & 15, kg = lane >> 4;

    short8 a[4][4], bfr[3][4];
    #pragma unroll
    for (int mi = 0; mi < 4; ++mi) {
        const unsigned short* ap = hb + (size_t)(mt * 64 + mi * 16 + rsel) * 128 + kg * 8;
        #pragma unroll
        for (int ks = 0; ks < 4; ++ks) a[mi][ks] = *(const short8*)(ap + ks * 32);
    }
    #pragma unroll
    for (int ni = 0; ni < 3; ++ni) {
        const unsigned short* bp = w2b + (size_t)(nt * 48 + ni * 16 + rsel) * 128 + kg * 8;
        #pragma unroll
        for (int ks = 0; ks < 4; ++ks) bfr[ni][ks] = *(const short8*)(bp + ks * 32);
    }
    floatx4 acc[4][3];
    #pragma unroll
    for (int mi = 0; mi < 4; ++mi)
        #pragma unroll
        for (int ni = 0; ni < 3; ++ni)
            acc[mi][ni] = (floatx4){0.f, 0.f, 0.f, 0.f};

    #pragma unroll
    for (int ks = 0; ks < 4; ++ks)
        #pragma unroll
        for (int mi = 0; mi < 4; ++mi)
            #pragma unroll
            for (int ni = 0; ni < 3; ++ni)
                acc[mi][ni] = __builtin_amdgcn_mfma_f32_16x16x32_bf16(
                    a[mi][ks], bfr[ni][ks], acc[mi][ni], 0, 0, 0);

    #pragma unroll
    for (int ni = 0; ni < 3; ++ni) {
        float bias = b2[nt * 48 + ni * 16 + rsel];
        #pragma unroll
        for (int mi = 0; mi < 4; ++mi) {
            #pragma unroll
            for (int r = 0; r < 4; ++r) {
                int m = mt * 64 + mi * 16 + kg * 4 + r;
                xd[(size_t)m * 1200 + nt * 48 + ni * 16 + rsel] = acc[mi][ni][r] + bias;
            }
        }
    }
}

#define GIDX(i, j) ((i) * 5 - (i) * ((i) - 1) / 2 + ((j) - (i)))
#define GF(i, j) Gm[((i) <= (j)) ? GIDX(i, j) : GIDX(j, i)]

// ---------------- Kernel C: conv(6->15) + Gram-space GS via LDS w-buffer ----------------
// 256 threads / sample. Conv: 250 threads, each owns channel-group g=t/50 (3 ch) and a
// row-pair of quads (rows 2s,2s+1 at col xq): live accs = 24. Output w staged in LDS
// [15][404]; Gram + combine re-read it (conflict-free float4s). No phase keeps >~60 regs.
__global__ __launch_bounds__(256, 4) void conv_gs_kernel(const float* __restrict__ xd,
                                                         const float* __restrict__ xres,
                                                         const float* __restrict__ cw,
                                                         const float* __restrict__ cb,
                                                         float* __restrict__ out) {
    const int b = blockIdx.x;
    const int tid = threadIdx.x;  // 0..255
    const int lane = tid & 63, wvid = tid >> 6;
    __shared__ __align__(16) float xpad[2908];     // 6 padded 22x22 planes
    __shared__ __align__(16) float wl[15 * 404];   // conv output, row stride 404 (101 f4)
    __shared__ float cwl[810];                     // weights as [ci][ky][tap][o]
    __shared__ float gred[2][16];

    // zero xpad (727 float4)
    float4* xf4 = (float4*)xpad;
    #pragma unroll
    for (int i = 0; i < 3; ++i) {
        int idx = tid + i * 256;
        if (idx < 727) xf4[idx] = make_float4(0.f, 0.f, 0.f, 0.f);
    }
    // stage transposed weights: cwl[(ci*9+ky*3+tap)*15 + o] = cw[o*54 + ci*9+ky*3+tap]
    #pragma unroll
    for (int i = 0; i < 4; ++i) {
        int idx = tid + i * 256;
        if (idx < 810) cwl[idx] = cw[(idx % 15) * 54 + idx / 15];
    }
    __syncthreads();

    // fill xpad interior (600 float4: ch 0-2 = xd, 3-5 = xres)
    const float* src0 = xd + (size_t)b * 1200;
    const float* src1 = xres + (size_t)b * 1200;
    #pragma unroll
    for (int i = 0; i < 3; ++i) {
        int j = tid + i * 256;
        if (j < 600) {
            float4 v = (j < 300) ? ((const float4*)src0)[j] : ((const float4*)src1)[j - 300];
            int c = j / 100, rr = (j % 100) * 4, y = rr / 20, x = rr % 20;
            float* dst = xpad + c * 484 + (y + 1) * 22 + (x + 1);
            dst[0] = v.x; dst[1] = v.y; dst[2] = v.z; dst[3] = v.w;
        }
    }
    __syncthreads();

    // ---- conv phase ----
    if (tid < 250) {
        const int g = tid / 50, s = tid % 50;
        const int r2 = s / 5, xc = s % 5;
        const int y0 = 2 * r2, xq = 4 * xc;
        const int o0 = 3 * g;
        const int q0 = y0 * 5 + xc, q1 = q0 + 5;
        const int wbase = y0 * 22 + xq;

        float a0[3][4], a1[3][4];  // [cc][slot] for quad0 (row y0), quad1 (row y0+1)
        #pragma unroll
        for (int cc = 0; cc < 3; ++cc) {
            float bo = cb[o0 + cc];
            #pragma unroll
            for (int sl = 0; sl < 4; ++sl) { a0[cc][sl] = bo; a1[cc][sl] = bo; }
        }

        #pragma unroll
        for (int ci = 0; ci < 6; ++ci) {
            // window rows y0..y0+3 of this input plane
            float P[4][6];
            #pragma unroll
            for (int rr = 0; rr < 4; ++rr) {
                const float* rp = xpad + ci * 484 + (y0 + rr) * 22 + xq;
                #pragma unroll
                for (int t = 0; t < 6; ++t) P[rr][t] = rp[t];
            }
            #pragma unroll
            for (int ky = 0; ky < 3; ++ky) {
                const float* wt = cwl + (ci * 9 + ky * 3) * 15 + o0;  // [tap][cc]
                #pragma unroll
                for (int cc = 0; cc < 3; ++cc) {
                    float w0 = wt[cc], w1v = wt[15 + cc], w2v = wt[30 + cc];
                    #pragma unroll
                    for (int sl = 0; sl < 4; ++sl) {
                        a0[cc][sl] = fmaf(P[ky][sl], w0,
                                     fmaf(P[ky][sl + 1], w1v,
                                     fmaf(P[ky][sl + 2], w2v, a0[cc][sl])));
                        a1[cc][sl] = fmaf(P[ky + 1][sl], w0,
                                     fmaf(P[ky + 1][sl + 1], w1v,
                                     fmaf(P[ky + 1][sl + 2], w2v, a1[cc][sl])));
                    }
                }
            }
        }
        #pragma unroll
        for (int cc = 0; cc < 3; ++cc) {
            *(float4*)(wl + (o0 + cc) * 404 + 4 * q0) =
                make_float4(a0[cc][0], a0[cc][1], a0[cc][2], a0[cc][3]);
            *(float4*)(wl + (o0 + cc) * 404 + 4 * q1) =
                make_float4(a1[cc][0], a1[cc][1], a1[cc][2], a1[cc][3]);
        }
    }
    __syncthreads();

    // ---- Gram phase: 15 pair-dots reduced once ----
    float g15[15];
    #pragma unroll
    for (int v = 0; v < 15; ++v) g15[v] = 0.f;
    if (tid < 100) {
        const int q4 = 4 * tid;
        #pragma unroll
        for (int cc = 0; cc < 3; ++cc) {
            float4 c0 = *(const float4*)(wl + (0 + cc) * 404 + q4);
            float4 c1 = *(const float4*)(wl + (3 + cc) * 404 + q4);
            float4 c2 = *(const float4*)(wl + (6 + cc) * 404 + q4);
            float4 c3 = *(const float4*)(wl + (9 + cc) * 404 + q4);
            float4 c4 = *(const float4*)(wl + (12 + cc) * 404 + q4);
            float4 ch[5] = {c0, c1, c2, c3, c4};
            int p = 0;
            #pragma unroll
            for (int i = 0; i < 5; ++i) {
                #pragma unroll
                for (int j = i; j < 5; ++j, ++p) {
                    g15[p] = fmaf(ch[i].x, ch[j].x,
                             fmaf(ch[i].y, ch[j].y,
                             fmaf(ch[i].z, ch[j].z,
                             fmaf(ch[i].w, ch[j].w, g15[p]))));
                }
            }
        }
    }
    if (wvid < 2) {
        #pragma unroll
        for (int m = 32; m; m >>= 1) {
            #pragma unroll
            for (int v = 0; v < 15; ++v) g15[v] += __shfl_xor(g15[v], m, 64);
        }
        if (lane == 0) {
            #pragma unroll
            for (int v = 0; v < 15; ++v) gred[wvid][v] = g15[v];
        }
    }
    __syncthreads();

    // ---- A-matrix (Gram-space modified GS) + combine + store ----
    if (tid < 100) {
        float Gm[15];
        #pragma unroll
        for (int v = 0; v < 15; ++v) Gm[v] = gred[0][v] + gred[1][v];

        float A[5][5];
        #pragma unroll
        for (int i = 0; i < 5; ++i)
            #pragma unroll
            for (int j = 0; j < 5; ++j) A[i][j] = (i == j) ? 1.f : 0.f;
        #pragma unroll
        for (int j = 0; j < 4; ++j) {
            float v[5];
            #pragma unroll
            for (int r = 0; r < 5; ++r) {
                float s0 = 0.f;
                #pragma unroll
                for (int k = 0; k < 5; ++k)
                    if (k <= j) s0 = fmaf(A[j][k], GF(k, r), s0);
                v[r] = s0;
            }
            float dj = 0.f;
            #pragma unroll
            for (int k = 0; k < 5; ++k)
                if (k <= j) dj = fmaf(A[j][k], v[k], dj);
            float rd = 1.0f / dj;
            #pragma unroll
            for (int i = j + 1; i < 5; ++i) {
                float cij = 0.f;
                #pragma unroll
                for (int k = 0; k < 5; ++k)
                    if (k <= i) cij = fmaf(A[i][k], v[k], cij);
                cij *= rd;
                #pragma unroll
                for (int k = 0; k < 5; ++k)
                    if (k <= j) A[i][k] = fmaf(-cij, A[j][k], A[i][k]);
            }
        }

        const int q4 = 4 * tid;
        float* ob = out + (size_t)b * 6000 + q4;
        #pragma unroll
        for (int cc = 0; cc < 3; ++cc) {
            float4 wq[5];
            #pragma unroll
            for (int k = 0; k < 5; ++k)
                wq[k] = *(const float4*)(wl + (3 * k + cc) * 404 + q4);
            #pragma unroll
            for (int d = 4; d >= 0; --d) {
                float4 u = wq[d];
                #pragma unroll
                for (int k = 0; k < d; ++k) {
                    u.x = fmaf(A[d][k], wq[k].x, u.x);
                    u.y = fmaf(A[d][k], wq[k].y, u.y);
                    u.z = fmaf(A[d][k], wq[k].z, u.z);
                    u.w = fmaf(A[d][k], wq[k].w, u.w);
                }
                *(float4*)(ob + (3 * d + cc) * 400) = u;
            }
        }
    }
}

extern "C" void kernel_launch(void* const* d_in, const int* in_sizes, int n_in,
                              void* d_out, int out_size, void* d_ws, size_t ws_size,
                              hipStream_t stream) {
    const float* x_restored  = (const float*)d_in[0];
    const float* x_distorted = (const float*)d_in[1];
    const float* w1          = (const float*)d_in[2];
    const float* w2          = (const float*)d_in[3];
    const float* b2          = (const float*)d_in[4];
    const float* conv_w      = (const float*)d_in[5];
    const float* conv_b      = (const float*)d_in[6];
    float* out = (float*)d_out;

    float* xd = (float*)d_ws;                                         // 39.3 MB
    unsigned short* hb  = (unsigned short*)(xd + (size_t)NB * 1200);  // 2 MB
    unsigned short* w2b = hb + (size_t)NB * 128;                      // 0.3 MB

    mlp1_kernel<<<(NB * 128) / 256, 256, 0, stream>>>(x_distorted, w1, hb);
    castw2_kernel<<<(1200 * 128) / 256, 256, 0, stream>>>(w2, w2b);
    mlp2_mfma<<<(128 * 25) / 4, 256, 0, stream>>>(hb, w2b, b2, xd);
    conv_gs_kernel<<<NB, 256, 0, stream>>>(xd, x_restored, conv_w, conv_b, out);
}